// Round 1
// baseline (445.297 us; speedup 1.0000x reference)
//
#include <hip/hip_runtime.h>
#include <hip/hip_bf16.h>

#define NH 24
#define HD 128
#define DM 3072
#define NB 2
#define SN 256
#define MR 512            // NB*SN rows
#define SCACHE 8192
#define NCH 9             // 8 cache chunks of 1024 + 1 new chunk of 256

typedef float f32x4 __attribute__((ext_vector_type(4)));
typedef float f32x2 __attribute__((ext_vector_type(2)));
typedef short s16x8 __attribute__((ext_vector_type(8)));
typedef short s16x4 __attribute__((ext_vector_type(4)));

__device__ __forceinline__ short bfc(float f) {
    __hip_bfloat16 h = __float2bfloat16(f);
    return __builtin_bit_cast(short, h);
}

// ---------------- GEMM: O[m,n] = sum_k A[m,k]*W[n,k] + bias[n] ----------------
// M=512, N=3072, K=3072. Tile 128x128, BK=64, 256 thr (4 waves), wave tile 64x64.
__global__ __launch_bounds__(256) void gemm_bias(
    const float* __restrict__ A,
    const float* __restrict__ W0, const float* __restrict__ W1, const float* __restrict__ W2,
    const float* __restrict__ b0, const float* __restrict__ b1, const float* __restrict__ b2,
    float* __restrict__ O0, float* __restrict__ O1, float* __restrict__ O2)
{
    const int z = blockIdx.z;
    const float* W    = (z == 0) ? W0 : (z == 1) ? W1 : W2;
    const float* bias = (z == 0) ? b0 : (z == 1) ? b1 : b2;
    float* O          = (z == 0) ? O0 : (z == 1) ? O1 : O2;

    const int n0 = blockIdx.x * 128;
    const int m0 = blockIdx.y * 128;
    const int t = threadIdx.x;
    const int lane = t & 63;
    const int wave = t >> 6;
    const int l15 = lane & 15, l4 = lane >> 4;
    const int wm = (wave >> 1) * 64, wn = (wave & 1) * 64;

    __shared__ short As[128][72];   // 64 bf16 + pad8 (stride 144B, 16B-aligned, 2-way banks)
    __shared__ short Bs[128][72];

    f32x4 acc[4][4] = {};

    for (int k0 = 0; k0 < DM; k0 += 64) {
        #pragma unroll
        for (int i = 0; i < 8; ++i) {
            int lin = i * 256 + t;
            int row = lin >> 4;
            int cc = (lin & 15) * 4;
            f32x4 av = *(const f32x4*)(A + (size_t)(m0 + row) * DM + k0 + cc);
            f32x4 wv = *(const f32x4*)(W + (size_t)(n0 + row) * DM + k0 + cc);
            s16x4 a4, w4;
            #pragma unroll
            for (int j = 0; j < 4; ++j) { a4[j] = bfc(av[j]); w4[j] = bfc(wv[j]); }
            *(s16x4*)&As[row][cc] = a4;
            *(s16x4*)&Bs[row][cc] = w4;
        }
        __syncthreads();
        s16x8 af[4][2], bfr[4][2];
        #pragma unroll
        for (int kt = 0; kt < 2; ++kt)
            #pragma unroll
            for (int i = 0; i < 4; ++i) {
                af[i][kt]  = *(const s16x8*)&As[wm + i * 16 + l15][kt * 32 + l4 * 8];
                bfr[i][kt] = *(const s16x8*)&Bs[wn + i * 16 + l15][kt * 32 + l4 * 8];
            }
        #pragma unroll
        for (int kt = 0; kt < 2; ++kt)
            #pragma unroll
            for (int mi = 0; mi < 4; ++mi)
                #pragma unroll
                for (int ni = 0; ni < 4; ++ni)
                    acc[mi][ni] = __builtin_amdgcn_mfma_f32_16x16x32_bf16(
                        af[mi][kt], bfr[ni][kt], acc[mi][ni], 0, 0, 0);
        __syncthreads();
    }

    #pragma unroll
    for (int ni = 0; ni < 4; ++ni) {
        int col = n0 + wn + ni * 16 + l15;
        float bv = bias[col];
        #pragma unroll
        for (int mi = 0; mi < 4; ++mi) {
            int row = m0 + wm + mi * 16 + l4 * 4;
            #pragma unroll
            for (int r = 0; r < 4; ++r)
                O[(size_t)(row + r) * DM + col] = acc[mi][ni][r] + bv;
        }
    }
}

// ---------------- RMSNorm (full 3072 row) + RoPE (interleaved pairs) ----------------
// grid 1024: blockIdx>>9 = buf (0=q -> writes bf16, 1=k -> in-place fp32), 256 thr/row.
__global__ __launch_bounds__(256) void norm_rope(
    float* __restrict__ qf, float* __restrict__ kf, short* __restrict__ qbf,
    const float* __restrict__ gq, const float* __restrict__ gk,
    const float* __restrict__ freqs)
{
    const int buf = blockIdx.x >> 9;
    const int row = blockIdx.x & 511;
    const int t = threadIdx.x;
    float* src = buf ? kf : qf;
    const float* g = buf ? gk : gq;

    f32x2 v[6];
    float ss = 0.f;
    #pragma unroll
    for (int i = 0; i < 6; ++i) {
        int p = t + 256 * i;
        v[i] = *(const f32x2*)(src + (size_t)row * DM + 2 * p);
        ss += v[i][0] * v[i][0] + v[i][1] * v[i][1];
    }
    #pragma unroll
    for (int m = 1; m < 64; m <<= 1) ss += __shfl_xor(ss, m);
    __shared__ float red[4];
    if ((t & 63) == 0) red[t >> 6] = ss;
    __syncthreads();
    ss = red[0] + red[1] + red[2] + red[3];
    const float scale = rsqrtf(ss * (1.0f / DM) + 1e-6f);

    const int spos = row & 255;
    #pragma unroll
    for (int i = 0; i < 6; ++i) {
        int p = t + 256 * i;
        int d2 = p & 63;
        float fr = freqs[spos * 64 + d2];
        float sn, cs;
        __sincosf(fr, &sn, &cs);
        f32x2 gg = *(const f32x2*)(g + 2 * p);
        float re = v[i][0] * scale * gg[0];
        float im = v[i][1] * scale * gg[1];
        float re2 = re * cs - im * sn;
        float im2 = re * sn + im * cs;
        if (buf == 0) {
            unsigned pack = (unsigned)(unsigned short)bfc(re2)
                          | ((unsigned)(unsigned short)bfc(im2) << 16);
            *(unsigned*)(qbf + (size_t)row * DM + 2 * p) = pack;
        } else {
            f32x2 o; o[0] = re2; o[1] = im2;
            *(f32x2*)(src + (size_t)row * DM + 2 * p) = o;
        }
    }
}

// ---------------- Flash attention partials ----------------
// grid (48 bh, 9 chunks), 512 thr (8 waves); wave owns 32 q rows; key tiles of 64.
__global__ __launch_bounds__(512) void attn_fa(
    const short* __restrict__ qbf, const float* __restrict__ kf, const float* __restrict__ vf,
    const float* __restrict__ kcache, const float* __restrict__ vcache,
    float* __restrict__ partO, float* __restrict__ partM, float* __restrict__ partL)
{
    const int bh = blockIdx.x;           // 0..47
    const int c  = blockIdx.y;           // 0..8
    const int b = bh / NH, h = bh % NH;
    const int t = threadIdx.x, lane = t & 63, wave = t >> 6;
    const int l15 = lane & 15, l4 = lane >> 4;
    const int hoff = h * HD;

    __shared__ short Ks[64][136];        // [kk][d], stride 272B
    __shared__ short Vt[128][72];        // [d][kk], stride 144B
    __shared__ short Pl[8][32][72];      // per-wave P [q][kk]

    // Q fragments (A-operand), bf16 direct from global
    s16x8 qa[2][4];
    #pragma unroll
    for (int mi = 0; mi < 2; ++mi) {
        int qrow = b * SN + wave * 32 + mi * 16 + l15;
        #pragma unroll
        for (int kt = 0; kt < 4; ++kt)
            qa[mi][kt] = *(const s16x8*)(qbf + (size_t)qrow * DM + hoff + kt * 32 + l4 * 8);
    }

    f32x4 acc[2][8] = {};
    float mrun[2][4], lrun[2][4];
    #pragma unroll
    for (int mi = 0; mi < 2; ++mi)
        #pragma unroll
        for (int r = 0; r < 4; ++r) { mrun[mi][r] = -INFINITY; lrun[mi][r] = 0.f; }

    const int NT = (c < 8) ? 16 : 4;
    const float* ksrc; const float* vsrc; int row0;
    if (c < 8) { ksrc = kcache + (size_t)b * SCACHE * DM; vsrc = vcache + (size_t)b * SCACHE * DM; row0 = c * 1024; }
    else       { ksrc = kf + (size_t)b * SN * DM;         vsrc = vf + (size_t)b * SN * DM;         row0 = 0; }

    const float SCL = 0.08838834764831845f * 1.4426950408889634f; // 1/sqrt(128)*log2e

    for (int nt = 0; nt < NT; ++nt) {
        const int kr0 = row0 + nt * 64;
        // stage K tile (row-major)
        #pragma unroll
        for (int i = 0; i < 4; ++i) {
            int lin = i * 512 + t;
            int row = lin >> 5;
            int cc = (lin & 31) * 4;
            f32x4 kv = *(const f32x4*)(ksrc + (size_t)(kr0 + row) * DM + hoff + cc);
            s16x4 k4;
            #pragma unroll
            for (int j = 0; j < 4; ++j) k4[j] = bfc(kv[j]);
            *(s16x4*)&Ks[row][cc] = k4;
        }
        // stage V transposed: thread -> one key column slice
        {
            int kk = t & 63, dblk = t >> 6;
            #pragma unroll
            for (int j = 0; j < 4; ++j) {
                int d0 = dblk * 16 + j * 4;
                f32x4 vv = *(const f32x4*)(vsrc + (size_t)(kr0 + kk) * DM + hoff + d0);
                #pragma unroll
                for (int jj = 0; jj < 4; ++jj) Vt[d0 + jj][kk] = bfc(vv[jj]);
            }
        }
        __syncthreads();

        // Q K^T
        f32x4 s[2][4] = {};
        #pragma unroll
        for (int kt = 0; kt < 4; ++kt)
            #pragma unroll
            for (int ni = 0; ni < 4; ++ni) {
                s16x8 kb = *(const s16x8*)&Ks[ni * 16 + l15][kt * 32 + l4 * 8];
                s[0][ni] = __builtin_amdgcn_mfma_f32_16x16x32_bf16(qa[0][kt], kb, s[0][ni], 0, 0, 0);
                s[1][ni] = __builtin_amdgcn_mfma_f32_16x16x32_bf16(qa[1][kt], kb, s[1][ni], 0, 0, 0);
            }

        // online softmax (log2 domain) + write P
        #pragma unroll
        for (int mi = 0; mi < 2; ++mi) {
            #pragma unroll
            for (int ni = 0; ni < 4; ++ni) s[mi][ni] *= SCL;
            #pragma unroll
            for (int r = 0; r < 4; ++r) {
                float lm = fmaxf(fmaxf(s[mi][0][r], s[mi][1][r]), fmaxf(s[mi][2][r], s[mi][3][r]));
                lm = fmaxf(lm, __shfl_xor(lm, 1));
                lm = fmaxf(lm, __shfl_xor(lm, 2));
                lm = fmaxf(lm, __shfl_xor(lm, 4));
                lm = fmaxf(lm, __shfl_xor(lm, 8));
                float mnew = fmaxf(mrun[mi][r], lm);
                float corr = exp2f(mrun[mi][r] - mnew);
                mrun[mi][r] = mnew;
                float rs = 0.f;
                #pragma unroll
                for (int ni = 0; ni < 4; ++ni) {
                    float p = exp2f(s[mi][ni][r] - mnew);
                    rs += p;
                    Pl[wave][mi * 16 + l4 * 4 + r][ni * 16 + l15] = bfc(p);
                }
                rs += __shfl_xor(rs, 1);
                rs += __shfl_xor(rs, 2);
                rs += __shfl_xor(rs, 4);
                rs += __shfl_xor(rs, 8);
                lrun[mi][r] = lrun[mi][r] * corr + rs;
                #pragma unroll
                for (int nd = 0; nd < 8; ++nd) acc[mi][nd][r] *= corr;
            }
        }

        // P V  (per-wave P in LDS; same-wave RAW ordered by lgkmcnt)
        #pragma unroll
        for (int kt2 = 0; kt2 < 2; ++kt2) {
            s16x8 pf0 = *(const s16x8*)&Pl[wave][l15][kt2 * 32 + l4 * 8];
            s16x8 pf1 = *(const s16x8*)&Pl[wave][16 + l15][kt2 * 32 + l4 * 8];
            #pragma unroll
            for (int nd = 0; nd < 8; ++nd) {
                s16x8 vb = *(const s16x8*)&Vt[nd * 16 + l15][kt2 * 32 + l4 * 8];
                acc[0][nd] = __builtin_amdgcn_mfma_f32_16x16x32_bf16(pf0, vb, acc[0][nd], 0, 0, 0);
                acc[1][nd] = __builtin_amdgcn_mfma_f32_16x16x32_bf16(pf1, vb, acc[1][nd], 0, 0, 0);
            }
        }
        __syncthreads();
    }

    // write partials
    const int pbase = (c * 48 + bh) * SN;
    #pragma unroll
    for (int mi = 0; mi < 2; ++mi)
        #pragma unroll
        for (int r = 0; r < 4; ++r) {
            int qrow = wave * 32 + mi * 16 + l4 * 4 + r;
            #pragma unroll
            for (int nd = 0; nd < 8; ++nd)
                partO[((size_t)(pbase + qrow)) * HD + nd * 16 + l15] = acc[mi][nd][r];
            if (l15 == 0) {
                partM[pbase + qrow] = mrun[mi][r];
                partL[pbase + qrow] = lrun[mi][r];
            }
        }
}

// ---------------- combine split-K partials ----------------
__global__ __launch_bounds__(128) void combine(
    const float* __restrict__ partO, const float* __restrict__ partM,
    const float* __restrict__ partL, float* __restrict__ attn)
{
    const int rowid = blockIdx.x;        // bh*256 + q
    const int bh = rowid >> 8, q = rowid & 255;
    const int b = bh / NH, h = bh % NH;
    const int d = threadIdx.x;

    float m[NCH];
    float M = -INFINITY;
    #pragma unroll
    for (int c = 0; c < NCH; ++c) { m[c] = partM[(c * 48 + bh) * SN + q]; M = fmaxf(M, m[c]); }
    float L = 0.f, o = 0.f;
    #pragma unroll
    for (int c = 0; c < NCH; ++c) {
        float w = exp2f(m[c] - M);
        L += partL[(c * 48 + bh) * SN + q] * w;
        o += partO[((size_t)((c * 48 + bh) * SN + q)) * HD + d] * w;
    }
    attn[(size_t)(b * SN + q) * DM + h * HD + d] = o / L;
}

extern "C" void kernel_launch(void* const* d_in, const int* in_sizes, int n_in,
                              void* d_out, int out_size, void* d_ws, size_t ws_size,
                              hipStream_t stream) {
    const float* x      = (const float*)d_in[0];
    const float* freqs  = (const float*)d_in[1];
    const float* kcache = (const float*)d_in[2];
    const float* vcache = (const float*)d_in[3];
    const float* Wq = (const float*)d_in[4];
    const float* bq = (const float*)d_in[5];
    const float* Wk = (const float*)d_in[6];
    const float* bk = (const float*)d_in[7];
    const float* Wv = (const float*)d_in[8];
    const float* bv = (const float*)d_in[9];
    const float* Wo = (const float*)d_in[10];
    const float* bo = (const float*)d_in[11];
    const float* gq = (const float*)d_in[12];
    const float* gk = (const float*)d_in[13];
    float* out = (float*)d_out;

    char* ws = (char*)d_ws;
    float* qf   = (float*)ws; ws += (size_t)MR * DM * 4;
    float* kfb  = (float*)ws; ws += (size_t)MR * DM * 4;
    float* vfb  = (float*)ws; ws += (size_t)MR * DM * 4;
    short* qbf  = (short*)ws; ws += (size_t)MR * DM * 2;
    float* pO   = (float*)ws; ws += (size_t)NCH * 48 * SN * HD * 4;
    float* pM   = (float*)ws; ws += (size_t)NCH * 48 * SN * 4;
    float* pL   = (float*)ws; ws += (size_t)NCH * 48 * SN * 4;
    float* attn = (float*)ws; ws += (size_t)MR * DM * 4;

    gemm_bias<<<dim3(24, 4, 3), 256, 0, stream>>>(x, Wq, Wk, Wv, bq, bk, bv, qf, kfb, vfb);
    norm_rope<<<dim3(1024), 256, 0, stream>>>(qf, kfb, qbf, gq, gk, freqs);
    attn_fa<<<dim3(48, NCH), 512, 0, stream>>>(qbf, kfb, vfb, kcache, vcache, pO, pM, pL);
    combine<<<dim3(12288), 128, 0, stream>>>(pO, pM, pL, attn);
    gemm_bias<<<dim3(24, 4, 1), 256, 0, stream>>>(attn, Wo, Wo, Wo, bo, bo, bo, out, out, out);
}

// Round 2
// 407.034 us; speedup vs baseline: 1.0940x; 1.0940x over previous
//
#include <hip/hip_runtime.h>
#include <hip/hip_bf16.h>

#define NH 24
#define HD 128
#define DM 3072
#define NB 2
#define SN 256
#define MR 512            // NB*SN rows
#define SCACHE 8192
#define NCH 9             // 8 cache chunks of 1024 + 1 new chunk of 256

typedef float f32x4 __attribute__((ext_vector_type(4)));
typedef float f32x2 __attribute__((ext_vector_type(2)));
typedef short s16x8 __attribute__((ext_vector_type(8)));
typedef short s16x4 __attribute__((ext_vector_type(4)));

__device__ __forceinline__ short bfc(float f) {
    __hip_bfloat16 h = __float2bfloat16(f);
    return __builtin_bit_cast(short, h);
}

// ---------------- GEMM: O[m,n] = sum_k A[m,k]*W[n,k] + bias[n] ----------------
// M=512, N=3072, K=3072. Tile 128x128, BK=64, 256 thr (4 waves), wave tile 64x64.
// T14 reg-staged prefetch: loads for K-step ks+1 are in flight during MFMA of ks.
__global__ __launch_bounds__(256, 2) void gemm_bias(
    const float* __restrict__ A,
    const float* __restrict__ W0, const float* __restrict__ W1, const float* __restrict__ W2,
    const float* __restrict__ b0, const float* __restrict__ b1, const float* __restrict__ b2,
    float* __restrict__ O0, float* __restrict__ O1, float* __restrict__ O2)
{
    const int z = blockIdx.z;
    const float* W    = (z == 0) ? W0 : (z == 1) ? W1 : W2;
    const float* bias = (z == 0) ? b0 : (z == 1) ? b1 : b2;
    float* O          = (z == 0) ? O0 : (z == 1) ? O1 : O2;

    const int n0 = blockIdx.x * 128;
    const int m0 = blockIdx.y * 128;
    const int t = threadIdx.x;
    const int lane = t & 63;
    const int wave = t >> 6;
    const int l15 = lane & 15, l4 = lane >> 4;
    const int wm = (wave >> 1) * 64, wn = (wave & 1) * 64;

    __shared__ short As[128][72];   // 64 bf16 + pad8
    __shared__ short Bs[128][72];

    f32x4 acc[4][4] = {};
    f32x4 areg[8], breg[8];

    // prologue: issue loads for k0 = 0
    #pragma unroll
    for (int i = 0; i < 8; ++i) {
        int lin = i * 256 + t;
        int row = lin >> 4;
        int cc = (lin & 15) * 4;
        areg[i] = *(const f32x4*)(A + (size_t)(m0 + row) * DM + 0 + cc);
        breg[i] = *(const f32x4*)(W + (size_t)(n0 + row) * DM + 0 + cc);
    }

    for (int ks = 0; ks < DM / 64; ++ks) {
        // write prefetched regs -> LDS (compiler inserts vmcnt waits here)
        #pragma unroll
        for (int i = 0; i < 8; ++i) {
            int lin = i * 256 + t;
            int row = lin >> 4;
            int cc = (lin & 15) * 4;
            s16x4 a4, w4;
            #pragma unroll
            for (int j = 0; j < 4; ++j) { a4[j] = bfc(areg[i][j]); w4[j] = bfc(breg[i][j]); }
            *(s16x4*)&As[row][cc] = a4;
            *(s16x4*)&Bs[row][cc] = w4;
        }
        __syncthreads();
        // issue loads for next K-step; they fly across the MFMA region below
        if (ks + 1 < DM / 64) {
            int k0 = (ks + 1) * 64;
            #pragma unroll
            for (int i = 0; i < 8; ++i) {
                int lin = i * 256 + t;
                int row = lin >> 4;
                int cc = (lin & 15) * 4;
                areg[i] = *(const f32x4*)(A + (size_t)(m0 + row) * DM + k0 + cc);
                breg[i] = *(const f32x4*)(W + (size_t)(n0 + row) * DM + k0 + cc);
            }
        }
        #pragma unroll
        for (int kt = 0; kt < 2; ++kt) {
            s16x8 af[4], bfr[4];
            #pragma unroll
            for (int i = 0; i < 4; ++i) {
                af[i]  = *(const s16x8*)&As[wm + i * 16 + l15][kt * 32 + l4 * 8];
                bfr[i] = *(const s16x8*)&Bs[wn + i * 16 + l15][kt * 32 + l4 * 8];
            }
            #pragma unroll
            for (int mi = 0; mi < 4; ++mi)
                #pragma unroll
                for (int ni = 0; ni < 4; ++ni)
                    acc[mi][ni] = __builtin_amdgcn_mfma_f32_16x16x32_bf16(
                        af[mi], bfr[ni], acc[mi][ni], 0, 0, 0);
        }
        __syncthreads();
    }

    #pragma unroll
    for (int ni = 0; ni < 4; ++ni) {
        int col = n0 + wn + ni * 16 + l15;
        float bv = bias[col];
        #pragma unroll
        for (int mi = 0; mi < 4; ++mi) {
            int row = m0 + wm + mi * 16 + l4 * 4;
            #pragma unroll
            for (int r = 0; r < 4; ++r)
                O[(size_t)(row + r) * DM + col] = acc[mi][ni][r] + bv;
        }
    }
}

// ---------------- RMSNorm (full 3072 row) + RoPE (interleaved pairs) ----------------
__global__ __launch_bounds__(256) void norm_rope(
    float* __restrict__ qf, float* __restrict__ kf, short* __restrict__ qbf,
    const float* __restrict__ gq, const float* __restrict__ gk,
    const float* __restrict__ freqs)
{
    const int buf = blockIdx.x >> 9;
    const int row = blockIdx.x & 511;
    const int t = threadIdx.x;
    float* src = buf ? kf : qf;
    const float* g = buf ? gk : gq;

    f32x2 v[6];
    float ss = 0.f;
    #pragma unroll
    for (int i = 0; i < 6; ++i) {
        int p = t + 256 * i;
        v[i] = *(const f32x2*)(src + (size_t)row * DM + 2 * p);
        ss += v[i][0] * v[i][0] + v[i][1] * v[i][1];
    }
    #pragma unroll
    for (int m = 1; m < 64; m <<= 1) ss += __shfl_xor(ss, m);
    __shared__ float red[4];
    if ((t & 63) == 0) red[t >> 6] = ss;
    __syncthreads();
    ss = red[0] + red[1] + red[2] + red[3];
    const float scale = rsqrtf(ss * (1.0f / DM) + 1e-6f);

    const int spos = row & 255;
    #pragma unroll
    for (int i = 0; i < 6; ++i) {
        int p = t + 256 * i;
        int d2 = p & 63;
        float fr = freqs[spos * 64 + d2];
        float sn, cs;
        __sincosf(fr, &sn, &cs);
        f32x2 gg = *(const f32x2*)(g + 2 * p);
        float re = v[i][0] * scale * gg[0];
        float im = v[i][1] * scale * gg[1];
        float re2 = re * cs - im * sn;
        float im2 = re * sn + im * cs;
        if (buf == 0) {
            unsigned pack = (unsigned)(unsigned short)bfc(re2)
                          | ((unsigned)(unsigned short)bfc(im2) << 16);
            *(unsigned*)(qbf + (size_t)row * DM + 2 * p) = pack;
        } else {
            f32x2 o; o[0] = re2; o[1] = im2;
            *(f32x2*)(src + (size_t)row * DM + 2 * p) = o;
        }
    }
}

// ---------------- Flash attention partials ----------------
// grid (48 bh, 9 chunks), 512 thr (8 waves); wave owns 32 q rows; key tiles of 64.
// T14 reg-staged prefetch: K/V global loads for tile nt+1 fly during QK/softmax/PV of nt.
__global__ __launch_bounds__(512, 2) void attn_fa(
    const short* __restrict__ qbf, const float* __restrict__ kf, const float* __restrict__ vf,
    const float* __restrict__ kcache, const float* __restrict__ vcache,
    float* __restrict__ partO, float* __restrict__ partM, float* __restrict__ partL)
{
    const int bh = blockIdx.x;           // 0..47
    const int c  = blockIdx.y;           // 0..8
    const int b = bh / NH, h = bh % NH;
    const int t = threadIdx.x, lane = t & 63, wave = t >> 6;
    const int l15 = lane & 15, l4 = lane >> 4;
    const int hoff = h * HD;

    __shared__ short Ks[64][136];        // [kk][d]
    __shared__ short Vt[128][72];        // [d][kk]
    __shared__ short Pl[8][32][72];      // per-wave P [q][kk]

    // Q fragments (A-operand), bf16 direct from global
    s16x8 qa[2][4];
    #pragma unroll
    for (int mi = 0; mi < 2; ++mi) {
        int qrow = b * SN + wave * 32 + mi * 16 + l15;
        #pragma unroll
        for (int kt = 0; kt < 4; ++kt)
            qa[mi][kt] = *(const s16x8*)(qbf + (size_t)qrow * DM + hoff + kt * 32 + l4 * 8);
    }

    f32x4 acc[2][8] = {};
    float mrun[2][4], lrun[2][4];
    #pragma unroll
    for (int mi = 0; mi < 2; ++mi)
        #pragma unroll
        for (int r = 0; r < 4; ++r) { mrun[mi][r] = -INFINITY; lrun[mi][r] = 0.f; }

    const int NT = (c < 8) ? 16 : 4;
    const float* ksrc; const float* vsrc; int row0;
    if (c < 8) { ksrc = kcache + (size_t)b * SCACHE * DM; vsrc = vcache + (size_t)b * SCACHE * DM; row0 = c * 1024; }
    else       { ksrc = kf + (size_t)b * SN * DM;         vsrc = vf + (size_t)b * SN * DM;         row0 = 0; }

    const float SCL = 0.08838834764831845f * 1.4426950408889634f; // 1/sqrt(128)*log2e

    const int skk = t & 63, sdblk = t >> 6;   // V-stage coords
    f32x4 kreg[4], vreg[4];

    // prologue: issue tile-0 loads
    #pragma unroll
    for (int i = 0; i < 4; ++i) {
        int lin = i * 512 + t;
        kreg[i] = *(const f32x4*)(ksrc + (size_t)(row0 + (lin >> 5)) * DM + hoff + (lin & 31) * 4);
    }
    #pragma unroll
    for (int j = 0; j < 4; ++j)
        vreg[j] = *(const f32x4*)(vsrc + (size_t)(row0 + skk) * DM + hoff + sdblk * 16 + j * 4);

    for (int nt = 0; nt < NT; ++nt) {
        // write prefetched regs -> LDS (vmcnt waits happen here)
        #pragma unroll
        for (int i = 0; i < 4; ++i) {
            int lin = i * 512 + t;
            int row = lin >> 5;
            int cc = (lin & 31) * 4;
            s16x4 k4;
            #pragma unroll
            for (int j = 0; j < 4; ++j) k4[j] = bfc(kreg[i][j]);
            *(s16x4*)&Ks[row][cc] = k4;
        }
        #pragma unroll
        for (int j = 0; j < 4; ++j) {
            int d0 = sdblk * 16 + j * 4;
            #pragma unroll
            for (int jj = 0; jj < 4; ++jj) Vt[d0 + jj][skk] = bfc(vreg[j][jj]);
        }
        __syncthreads();

        // issue next-tile loads; they overlap the whole compute region below
        if (nt + 1 < NT) {
            const int kr1 = row0 + (nt + 1) * 64;
            #pragma unroll
            for (int i = 0; i < 4; ++i) {
                int lin = i * 512 + t;
                kreg[i] = *(const f32x4*)(ksrc + (size_t)(kr1 + (lin >> 5)) * DM + hoff + (lin & 31) * 4);
            }
            #pragma unroll
            for (int j = 0; j < 4; ++j)
                vreg[j] = *(const f32x4*)(vsrc + (size_t)(kr1 + skk) * DM + hoff + sdblk * 16 + j * 4);
        }

        // Q K^T
        f32x4 s[2][4] = {};
        #pragma unroll
        for (int kt = 0; kt < 4; ++kt)
            #pragma unroll
            for (int ni = 0; ni < 4; ++ni) {
                s16x8 kb = *(const s16x8*)&Ks[ni * 16 + l15][kt * 32 + l4 * 8];
                s[0][ni] = __builtin_amdgcn_mfma_f32_16x16x32_bf16(qa[0][kt], kb, s[0][ni], 0, 0, 0);
                s[1][ni] = __builtin_amdgcn_mfma_f32_16x16x32_bf16(qa[1][kt], kb, s[1][ni], 0, 0, 0);
            }

        // online softmax (log2 domain) + write P
        #pragma unroll
        for (int mi = 0; mi < 2; ++mi) {
            #pragma unroll
            for (int ni = 0; ni < 4; ++ni) s[mi][ni] *= SCL;
            #pragma unroll
            for (int r = 0; r < 4; ++r) {
                float lm = fmaxf(fmaxf(s[mi][0][r], s[mi][1][r]), fmaxf(s[mi][2][r], s[mi][3][r]));
                lm = fmaxf(lm, __shfl_xor(lm, 1));
                lm = fmaxf(lm, __shfl_xor(lm, 2));
                lm = fmaxf(lm, __shfl_xor(lm, 4));
                lm = fmaxf(lm, __shfl_xor(lm, 8));
                float mnew = fmaxf(mrun[mi][r], lm);
                float corr = exp2f(mrun[mi][r] - mnew);
                mrun[mi][r] = mnew;
                float rs = 0.f;
                #pragma unroll
                for (int ni = 0; ni < 4; ++ni) {
                    float p = exp2f(s[mi][ni][r] - mnew);
                    rs += p;
                    Pl[wave][mi * 16 + l4 * 4 + r][ni * 16 + l15] = bfc(p);
                }
                rs += __shfl_xor(rs, 1);
                rs += __shfl_xor(rs, 2);
                rs += __shfl_xor(rs, 4);
                rs += __shfl_xor(rs, 8);
                lrun[mi][r] = lrun[mi][r] * corr + rs;
                #pragma unroll
                for (int nd = 0; nd < 8; ++nd) acc[mi][nd][r] *= corr;
            }
        }

        // P V  (per-wave P in LDS; same-wave RAW ordered by lgkmcnt)
        #pragma unroll
        for (int kt2 = 0; kt2 < 2; ++kt2) {
            s16x8 pf0 = *(const s16x8*)&Pl[wave][l15][kt2 * 32 + l4 * 8];
            s16x8 pf1 = *(const s16x8*)&Pl[wave][16 + l15][kt2 * 32 + l4 * 8];
            #pragma unroll
            for (int nd = 0; nd < 8; ++nd) {
                s16x8 vb = *(const s16x8*)&Vt[nd * 16 + l15][kt2 * 32 + l4 * 8];
                acc[0][nd] = __builtin_amdgcn_mfma_f32_16x16x32_bf16(pf0, vb, acc[0][nd], 0, 0, 0);
                acc[1][nd] = __builtin_amdgcn_mfma_f32_16x16x32_bf16(pf1, vb, acc[1][nd], 0, 0, 0);
            }
        }
        __syncthreads();
    }

    // write partials
    const int pbase = (c * 48 + bh) * SN;
    #pragma unroll
    for (int mi = 0; mi < 2; ++mi)
        #pragma unroll
        for (int r = 0; r < 4; ++r) {
            int qrow = wave * 32 + mi * 16 + l4 * 4 + r;
            #pragma unroll
            for (int nd = 0; nd < 8; ++nd)
                partO[((size_t)(pbase + qrow)) * HD + nd * 16 + l15] = acc[mi][nd][r];
            if (l15 == 0) {
                partM[pbase + qrow] = mrun[mi][r];
                partL[pbase + qrow] = lrun[mi][r];
            }
        }
}

// ---------------- combine split-K partials ----------------
__global__ __launch_bounds__(128) void combine(
    const float* __restrict__ partO, const float* __restrict__ partM,
    const float* __restrict__ partL, float* __restrict__ attn)
{
    const int rowid = blockIdx.x;        // bh*256 + q
    const int bh = rowid >> 8, q = rowid & 255;
    const int b = bh / NH, h = bh % NH;
    const int d = threadIdx.x;

    float m[NCH];
    float M = -INFINITY;
    #pragma unroll
    for (int c = 0; c < NCH; ++c) { m[c] = partM[(c * 48 + bh) * SN + q]; M = fmaxf(M, m[c]); }
    float L = 0.f, o = 0.f;
    #pragma unroll
    for (int c = 0; c < NCH; ++c) {
        float w = exp2f(m[c] - M);
        L += partL[(c * 48 + bh) * SN + q] * w;
        o += partO[((size_t)((c * 48 + bh) * SN + q)) * HD + d] * w;
    }
    attn[(size_t)(b * SN + q) * DM + h * HD + d] = o / L;
}

extern "C" void kernel_launch(void* const* d_in, const int* in_sizes, int n_in,
                              void* d_out, int out_size, void* d_ws, size_t ws_size,
                              hipStream_t stream) {
    const float* x      = (const float*)d_in[0];
    const float* freqs  = (const float*)d_in[1];
    const float* kcache = (const float*)d_in[2];
    const float* vcache = (const float*)d_in[3];
    const float* Wq = (const float*)d_in[4];
    const float* bq = (const float*)d_in[5];
    const float* Wk = (const float*)d_in[6];
    const float* bk = (const float*)d_in[7];
    const float* Wv = (const float*)d_in[8];
    const float* bv = (const float*)d_in[9];
    const float* Wo = (const float*)d_in[10];
    const float* bo = (const float*)d_in[11];
    const float* gq = (const float*)d_in[12];
    const float* gk = (const float*)d_in[13];
    float* out = (float*)d_out;

    char* ws = (char*)d_ws;
    float* qf   = (float*)ws; ws += (size_t)MR * DM * 4;
    float* kfb  = (float*)ws; ws += (size_t)MR * DM * 4;
    float* vfb  = (float*)ws; ws += (size_t)MR * DM * 4;
    short* qbf  = (short*)ws; ws += (size_t)MR * DM * 2;
    float* pO   = (float*)ws; ws += (size_t)NCH * 48 * SN * HD * 4;
    float* pM   = (float*)ws; ws += (size_t)NCH * 48 * SN * 4;
    float* pL   = (float*)ws; ws += (size_t)NCH * 48 * SN * 4;
    float* attn = (float*)ws; ws += (size_t)MR * DM * 4;

    gemm_bias<<<dim3(24, 4, 3), 256, 0, stream>>>(x, Wq, Wk, Wv, bq, bk, bv, qf, kfb, vfb);
    norm_rope<<<dim3(1024), 256, 0, stream>>>(qf, kfb, qbf, gq, gk, freqs);
    attn_fa<<<dim3(48, NCH), 512, 0, stream>>>(qbf, kfb, vfb, kcache, vcache, pO, pM, pL);
    combine<<<dim3(12288), 128, 0, stream>>>(pO, pM, pL, attn);
    gemm_bias<<<dim3(24, 4, 1), 256, 0, stream>>>(attn, Wo, Wo, Wo, bo, bo, bo, out, out, out);
}

// Round 3
// 383.869 us; speedup vs baseline: 1.1600x; 1.0603x over previous
//
#include <hip/hip_runtime.h>
#include <hip/hip_bf16.h>

#define NH 24
#define HD 128
#define DM 3072
#define NB 2
#define SN 256
#define MR 512            // NB*SN rows
#define SCACHE 8192
#define NCH 9             // 8 cache chunks of 1024 + 1 new chunk of 256

typedef float f32x4 __attribute__((ext_vector_type(4)));
typedef float f32x2 __attribute__((ext_vector_type(2)));
typedef short s16x8 __attribute__((ext_vector_type(8)));
typedef short s16x4 __attribute__((ext_vector_type(4)));

__device__ __forceinline__ short bfc(float f) {
    __hip_bfloat16 h = __float2bfloat16(f);
    return __builtin_bit_cast(short, h);
}

// ---------------- GEMM: O[m,n] = sum_k A[m,k]*W[n,k] + bias[n] ----------------
// BM=64, BN=128, BK=64, 256 thr (4 waves), wave tile 32x64. Reg-staged prefetch.
// QKV: grid (24, 8, 3) = 576 blocks; out-proj: (24, 8, 1) = 192 blocks.
__global__ __launch_bounds__(256, 3) void gemm_bias(
    const float* __restrict__ A,
    const float* __restrict__ W0, const float* __restrict__ W1, const float* __restrict__ W2,
    const float* __restrict__ b0, const float* __restrict__ b1, const float* __restrict__ b2,
    float* __restrict__ O0, float* __restrict__ O1, float* __restrict__ O2)
{
    const int z = blockIdx.z;
    const float* W    = (z == 0) ? W0 : (z == 1) ? W1 : W2;
    const float* bias = (z == 0) ? b0 : (z == 1) ? b1 : b2;
    float* O          = (z == 0) ? O0 : (z == 1) ? O1 : O2;

    const int n0 = blockIdx.x * 128;
    const int m0 = blockIdx.y * 64;
    const int t = threadIdx.x;
    const int lane = t & 63;
    const int wave = t >> 6;
    const int l15 = lane & 15, l4 = lane >> 4;
    const int wm = (wave >> 1) * 32, wn = (wave & 1) * 64;

    __shared__ short As[64][72];    // 64 bf16 + pad8
    __shared__ short Bs[128][72];

    f32x4 acc[2][4] = {};
    f32x4 areg[4], breg[8];

    // prologue: issue loads for k0 = 0
    #pragma unroll
    for (int i = 0; i < 4; ++i) {
        int lin = i * 256 + t;
        areg[i] = *(const f32x4*)(A + (size_t)(m0 + (lin >> 4)) * DM + (lin & 15) * 4);
    }
    #pragma unroll
    for (int i = 0; i < 8; ++i) {
        int lin = i * 256 + t;
        breg[i] = *(const f32x4*)(W + (size_t)(n0 + (lin >> 4)) * DM + (lin & 15) * 4);
    }

    for (int ks = 0; ks < DM / 64; ++ks) {
        #pragma unroll
        for (int i = 0; i < 4; ++i) {
            int lin = i * 256 + t;
            s16x4 a4;
            #pragma unroll
            for (int j = 0; j < 4; ++j) a4[j] = bfc(areg[i][j]);
            *(s16x4*)&As[lin >> 4][(lin & 15) * 4] = a4;
        }
        #pragma unroll
        for (int i = 0; i < 8; ++i) {
            int lin = i * 256 + t;
            s16x4 w4;
            #pragma unroll
            for (int j = 0; j < 4; ++j) w4[j] = bfc(breg[i][j]);
            *(s16x4*)&Bs[lin >> 4][(lin & 15) * 4] = w4;
        }
        __syncthreads();
        if (ks + 1 < DM / 64) {
            int k0 = (ks + 1) * 64;
            #pragma unroll
            for (int i = 0; i < 4; ++i) {
                int lin = i * 256 + t;
                areg[i] = *(const f32x4*)(A + (size_t)(m0 + (lin >> 4)) * DM + k0 + (lin & 15) * 4);
            }
            #pragma unroll
            for (int i = 0; i < 8; ++i) {
                int lin = i * 256 + t;
                breg[i] = *(const f32x4*)(W + (size_t)(n0 + (lin >> 4)) * DM + k0 + (lin & 15) * 4);
            }
        }
        #pragma unroll
        for (int kt = 0; kt < 2; ++kt) {
            s16x8 af[2], bfr[4];
            #pragma unroll
            for (int i = 0; i < 2; ++i)
                af[i]  = *(const s16x8*)&As[wm + i * 16 + l15][kt * 32 + l4 * 8];
            #pragma unroll
            for (int i = 0; i < 4; ++i)
                bfr[i] = *(const s16x8*)&Bs[wn + i * 16 + l15][kt * 32 + l4 * 8];
            #pragma unroll
            for (int mi = 0; mi < 2; ++mi)
                #pragma unroll
                for (int ni = 0; ni < 4; ++ni)
                    acc[mi][ni] = __builtin_amdgcn_mfma_f32_16x16x32_bf16(
                        af[mi], bfr[ni], acc[mi][ni], 0, 0, 0);
        }
        __syncthreads();
    }

    #pragma unroll
    for (int ni = 0; ni < 4; ++ni) {
        int col = n0 + wn + ni * 16 + l15;
        float bv = bias[col];
        #pragma unroll
        for (int mi = 0; mi < 2; ++mi) {
            int row = m0 + wm + mi * 16 + l4 * 4;
            #pragma unroll
            for (int r = 0; r < 4; ++r)
                O[(size_t)(row + r) * DM + col] = acc[mi][ni][r] + bv;
        }
    }
}

// ---------------- RMSNorm (full 3072 row) + RoPE (interleaved pairs) ----------------
__global__ __launch_bounds__(256) void norm_rope(
    float* __restrict__ qf, float* __restrict__ kf, short* __restrict__ qbf,
    const float* __restrict__ gq, const float* __restrict__ gk,
    const float* __restrict__ freqs)
{
    const int buf = blockIdx.x >> 9;
    const int row = blockIdx.x & 511;
    const int t = threadIdx.x;
    float* src = buf ? kf : qf;
    const float* g = buf ? gk : gq;

    f32x2 v[6];
    float ss = 0.f;
    #pragma unroll
    for (int i = 0; i < 6; ++i) {
        int p = t + 256 * i;
        v[i] = *(const f32x2*)(src + (size_t)row * DM + 2 * p);
        ss += v[i][0] * v[i][0] + v[i][1] * v[i][1];
    }
    #pragma unroll
    for (int m = 1; m < 64; m <<= 1) ss += __shfl_xor(ss, m);
    __shared__ float red[4];
    if ((t & 63) == 0) red[t >> 6] = ss;
    __syncthreads();
    ss = red[0] + red[1] + red[2] + red[3];
    const float scale = rsqrtf(ss * (1.0f / DM) + 1e-6f);

    const int spos = row & 255;
    #pragma unroll
    for (int i = 0; i < 6; ++i) {
        int p = t + 256 * i;
        int d2 = p & 63;
        float fr = freqs[spos * 64 + d2];
        float sn, cs;
        __sincosf(fr, &sn, &cs);
        f32x2 gg = *(const f32x2*)(g + 2 * p);
        float re = v[i][0] * scale * gg[0];
        float im = v[i][1] * scale * gg[1];
        float re2 = re * cs - im * sn;
        float im2 = re * sn + im * cs;
        if (buf == 0) {
            unsigned pack = (unsigned)(unsigned short)bfc(re2)
                          | ((unsigned)(unsigned short)bfc(im2) << 16);
            *(unsigned*)(qbf + (size_t)row * DM + 2 * p) = pack;
        } else {
            f32x2 o; o[0] = re2; o[1] = im2;
            *(f32x2*)(src + (size_t)row * DM + 2 * p) = o;
        }
    }
}

// ---------------- Flash attention partials ----------------
// 1-D grid of 432 blocks, XCD-grouped swizzle: each XCD owns a contiguous
// (c, bh) span so the 24 heads x 2 batches of one chunk stream the SAME
// cache rows together -> full 12KB-row DRAM coverage instead of 512B islands.
__global__ __launch_bounds__(512, 2) void attn_fa(
    const short* __restrict__ qbf, const float* __restrict__ kf, const float* __restrict__ vf,
    const float* __restrict__ kcache, const float* __restrict__ vcache,
    float* __restrict__ partO, float* __restrict__ partM, float* __restrict__ partL)
{
    const int bid = blockIdx.x;               // 0..431
    const int linear = (bid & 7) * 54 + (bid >> 3);
    const int c  = linear / 48;               // 0..8
    const int bh = linear % 48;
    const int b = bh / NH, h = bh % NH;
    const int t = threadIdx.x, lane = t & 63, wave = t >> 6;
    const int l15 = lane & 15, l4 = lane >> 4;
    const int hoff = h * HD;

    __shared__ short Ks[64][136];        // [kk][d]
    __shared__ short Vt[128][72];        // [d][kk]
    __shared__ short Pl[8][32][72];      // per-wave P [q][kk]

    s16x8 qa[2][4];
    #pragma unroll
    for (int mi = 0; mi < 2; ++mi) {
        int qrow = b * SN + wave * 32 + mi * 16 + l15;
        #pragma unroll
        for (int kt = 0; kt < 4; ++kt)
            qa[mi][kt] = *(const s16x8*)(qbf + (size_t)qrow * DM + hoff + kt * 32 + l4 * 8);
    }

    f32x4 acc[2][8] = {};
    float mrun[2][4], lrun[2][4];
    #pragma unroll
    for (int mi = 0; mi < 2; ++mi)
        #pragma unroll
        for (int r = 0; r < 4; ++r) { mrun[mi][r] = -INFINITY; lrun[mi][r] = 0.f; }

    const int NT = (c < 8) ? 16 : 4;
    const float* ksrc; const float* vsrc; int row0;
    if (c < 8) { ksrc = kcache + (size_t)b * SCACHE * DM; vsrc = vcache + (size_t)b * SCACHE * DM; row0 = c * 1024; }
    else       { ksrc = kf + (size_t)b * SN * DM;         vsrc = vf + (size_t)b * SN * DM;         row0 = 0; }

    const float SCL = 0.08838834764831845f * 1.4426950408889634f; // 1/sqrt(128)*log2e

    const int skk = t & 63, sdblk = t >> 6;   // V-stage coords
    f32x4 kreg[4], vreg[4];

    #pragma unroll
    for (int i = 0; i < 4; ++i) {
        int lin = i * 512 + t;
        kreg[i] = *(const f32x4*)(ksrc + (size_t)(row0 + (lin >> 5)) * DM + hoff + (lin & 31) * 4);
    }
    #pragma unroll
    for (int j = 0; j < 4; ++j)
        vreg[j] = *(const f32x4*)(vsrc + (size_t)(row0 + skk) * DM + hoff + sdblk * 16 + j * 4);

    for (int nt = 0; nt < NT; ++nt) {
        #pragma unroll
        for (int i = 0; i < 4; ++i) {
            int lin = i * 512 + t;
            s16x4 k4;
            #pragma unroll
            for (int j = 0; j < 4; ++j) k4[j] = bfc(kreg[i][j]);
            *(s16x4*)&Ks[lin >> 5][(lin & 31) * 4] = k4;
        }
        #pragma unroll
        for (int j = 0; j < 4; ++j) {
            int d0 = sdblk * 16 + j * 4;
            #pragma unroll
            for (int jj = 0; jj < 4; ++jj) Vt[d0 + jj][skk] = bfc(vreg[j][jj]);
        }
        __syncthreads();

        if (nt + 1 < NT) {
            const int kr1 = row0 + (nt + 1) * 64;
            #pragma unroll
            for (int i = 0; i < 4; ++i) {
                int lin = i * 512 + t;
                kreg[i] = *(const f32x4*)(ksrc + (size_t)(kr1 + (lin >> 5)) * DM + hoff + (lin & 31) * 4);
            }
            #pragma unroll
            for (int j = 0; j < 4; ++j)
                vreg[j] = *(const f32x4*)(vsrc + (size_t)(kr1 + skk) * DM + hoff + sdblk * 16 + j * 4);
        }

        // Q K^T
        f32x4 s[2][4] = {};
        #pragma unroll
        for (int kt = 0; kt < 4; ++kt)
            #pragma unroll
            for (int ni = 0; ni < 4; ++ni) {
                s16x8 kb = *(const s16x8*)&Ks[ni * 16 + l15][kt * 32 + l4 * 8];
                s[0][ni] = __builtin_amdgcn_mfma_f32_16x16x32_bf16(qa[0][kt], kb, s[0][ni], 0, 0, 0);
                s[1][ni] = __builtin_amdgcn_mfma_f32_16x16x32_bf16(qa[1][kt], kb, s[1][ni], 0, 0, 0);
            }

        // online softmax (log2 domain) + write P
        #pragma unroll
        for (int mi = 0; mi < 2; ++mi) {
            #pragma unroll
            for (int ni = 0; ni < 4; ++ni) s[mi][ni] *= SCL;
            #pragma unroll
            for (int r = 0; r < 4; ++r) {
                float lm = fmaxf(fmaxf(s[mi][0][r], s[mi][1][r]), fmaxf(s[mi][2][r], s[mi][3][r]));
                lm = fmaxf(lm, __shfl_xor(lm, 1));
                lm = fmaxf(lm, __shfl_xor(lm, 2));
                lm = fmaxf(lm, __shfl_xor(lm, 4));
                lm = fmaxf(lm, __shfl_xor(lm, 8));
                float mnew = fmaxf(mrun[mi][r], lm);
                float corr = exp2f(mrun[mi][r] - mnew);
                mrun[mi][r] = mnew;
                float rs = 0.f;
                #pragma unroll
                for (int ni = 0; ni < 4; ++ni) {
                    float p = exp2f(s[mi][ni][r] - mnew);
                    rs += p;
                    Pl[wave][mi * 16 + l4 * 4 + r][ni * 16 + l15] = bfc(p);
                }
                rs += __shfl_xor(rs, 1);
                rs += __shfl_xor(rs, 2);
                rs += __shfl_xor(rs, 4);
                rs += __shfl_xor(rs, 8);
                lrun[mi][r] = lrun[mi][r] * corr + rs;
                #pragma unroll
                for (int nd = 0; nd < 8; ++nd) acc[mi][nd][r] *= corr;
            }
        }

        // P V
        #pragma unroll
        for (int kt2 = 0; kt2 < 2; ++kt2) {
            s16x8 pf0 = *(const s16x8*)&Pl[wave][l15][kt2 * 32 + l4 * 8];
            s16x8 pf1 = *(const s16x8*)&Pl[wave][16 + l15][kt2 * 32 + l4 * 8];
            #pragma unroll
            for (int nd = 0; nd < 8; ++nd) {
                s16x8 vb = *(const s16x8*)&Vt[nd * 16 + l15][kt2 * 32 + l4 * 8];
                acc[0][nd] = __builtin_amdgcn_mfma_f32_16x16x32_bf16(pf0, vb, acc[0][nd], 0, 0, 0);
                acc[1][nd] = __builtin_amdgcn_mfma_f32_16x16x32_bf16(pf1, vb, acc[1][nd], 0, 0, 0);
            }
        }
        __syncthreads();
    }

    // write partials, c innermost so combine reads contiguously
    #pragma unroll
    for (int mi = 0; mi < 2; ++mi)
        #pragma unroll
        for (int r = 0; r < 4; ++r) {
            int qrow = wave * 32 + mi * 16 + l4 * 4 + r;
            size_t rowid = (size_t)bh * SN + qrow;
            #pragma unroll
            for (int nd = 0; nd < 8; ++nd)
                partO[(rowid * NCH + c) * HD + nd * 16 + l15] = acc[mi][nd][r];
            if (l15 == 0) {
                partM[rowid * NCH + c] = mrun[mi][r];
                partL[rowid * NCH + c] = lrun[mi][r];
            }
        }
}

// ---------------- combine split-K partials (contiguous per-row reads) ----------------
__global__ __launch_bounds__(128) void combine(
    const float* __restrict__ partO, const float* __restrict__ partM,
    const float* __restrict__ partL, float* __restrict__ attn)
{
    const int rowid = blockIdx.x;        // bh*256 + q
    const int bh = rowid >> 8, q = rowid & 255;
    const int b = bh / NH, h = bh % NH;
    const int d = threadIdx.x;

    float m[NCH];
    float M = -INFINITY;
    #pragma unroll
    for (int c = 0; c < NCH; ++c) { m[c] = partM[(size_t)rowid * NCH + c]; M = fmaxf(M, m[c]); }
    float L = 0.f, o = 0.f;
    #pragma unroll
    for (int c = 0; c < NCH; ++c) {
        float w = exp2f(m[c] - M);
        L += partL[(size_t)rowid * NCH + c] * w;
        o += partO[((size_t)rowid * NCH + c) * HD + d] * w;
    }
    attn[(size_t)(b * SN + q) * DM + h * HD + d] = o / L;
}

extern "C" void kernel_launch(void* const* d_in, const int* in_sizes, int n_in,
                              void* d_out, int out_size, void* d_ws, size_t ws_size,
                              hipStream_t stream) {
    const float* x      = (const float*)d_in[0];
    const float* freqs  = (const float*)d_in[1];
    const float* kcache = (const float*)d_in[2];
    const float* vcache = (const float*)d_in[3];
    const float* Wq = (const float*)d_in[4];
    const float* bq = (const float*)d_in[5];
    const float* Wk = (const float*)d_in[6];
    const float* bk = (const float*)d_in[7];
    const float* Wv = (const float*)d_in[8];
    const float* bv = (const float*)d_in[9];
    const float* Wo = (const float*)d_in[10];
    const float* bo = (const float*)d_in[11];
    const float* gq = (const float*)d_in[12];
    const float* gk = (const float*)d_in[13];
    float* out = (float*)d_out;

    char* ws = (char*)d_ws;
    float* qf   = (float*)ws; ws += (size_t)MR * DM * 4;
    float* kfb  = (float*)ws; ws += (size_t)MR * DM * 4;
    float* vfb  = (float*)ws; ws += (size_t)MR * DM * 4;
    short* qbf  = (short*)ws; ws += (size_t)MR * DM * 2;
    float* pO   = (float*)ws; ws += (size_t)NCH * 48 * SN * HD * 4;
    float* pM   = (float*)ws; ws += (size_t)NCH * 48 * SN * 4;
    float* pL   = (float*)ws; ws += (size_t)NCH * 48 * SN * 4;
    float* attn = (float*)ws; ws += (size_t)MR * DM * 4;

    gemm_bias<<<dim3(24, 8, 3), 256, 0, stream>>>(x, Wq, Wk, Wv, bq, bk, bv, qf, kfb, vfb);
    norm_rope<<<dim3(1024), 256, 0, stream>>>(qf, kfb, qbf, gq, gk, freqs);
    attn_fa<<<dim3(432), 512, 0, stream>>>(qbf, kfb, vfb, kcache, vcache, pO, pM, pL);
    combine<<<dim3(12288), 128, 0, stream>>>(pO, pM, pL, attn);
    gemm_bias<<<dim3(24, 8, 1), 256, 0, stream>>>(attn, Wo, Wo, Wo, bo, bo, bo, out, out, out);
}